// Round 1
// 198.697 us; speedup vs baseline: 1.0001x; 1.0001x over previous
//
#include <hip/hip_runtime.h>

// Native clang vector: layout-identical to float4, accepted by nontemporal builtins.
typedef float vfloat4 __attribute__((ext_vector_type(4)));

namespace {
constexpr int kB = 8;
constexpr int kL = 4096;
constexpr int kD = 768;
constexpr int kW = 12;           // ATTN_WIDTH
constexpr int kHalo = kW - 1;    // 11
constexpr float kEps = 1e-7f;

constexpr int kT = 16;                   // output rows per block
constexpr int kRows = kT + kHalo;        // 27 rows touched per block
constexpr int kThreads = 192;            // 192*4 == kD
constexpr int kChunks = kL / kT;         // 256
constexpr int kGrid = kB * kChunks;      // 2048 blocks
}

// Fully fused: each block recomputes u for its 27 rows from the x rows it
// must load anyway, then does the banded normalize-and-accumulate.
// Eliminates the separate u = x@Wa streaming pass (100.7 MB HBM read).
//
// Numerics: phase A reproduces the old K1 EXACTLY — per-lane fp64 partial of
// 12 products (ascending k), then a 6-step fp64 butterfly over 64 lanes.
// wsum is summed in ascending j like the old K2. => bitwise-identical output.
__global__ __launch_bounds__(kThreads, 3) void fused_banded_kernel(
    const float* __restrict__ x, const float* __restrict__ Wa,
    float* __restrict__ out) {
  __shared__ double s_ud[kRows];   // fp64 u (for scale; cancellation-sensitive)
  __shared__ float s_uf[kRows];    // fp32 u (for the banded dot)
  __shared__ float s_scale[kT];

  const int blk = blockIdx.x;
  const int b = blk / kChunks;
  const int i0 = (blk % kChunks) * kT;
  const float* xb = x + (size_t)b * kL * kD;
  float* ob = out + (size_t)b * kL * kD;
  const int tid = threadIdx.x;
  const int lane = tid & 63;
  const int wv = tid >> 6;  // 0..2

  // ---------------- Phase A: u for rows i0-11 .. i0+15 ----------------
  // One full row per wave per step: lane l covers cols {4l+256k}, k=0..2.
  vfloat4 w[3];
#pragma unroll
  for (int k = 0; k < 3; ++k)
    w[k] = *(const vfloat4*)(Wa + 4 * lane + 256 * k);

  if (i0 >= kHalo) {
    // Hot path (2040/2048 blocks): no row guards; issue all 27 loads per
    // wave before any math, then 9 independent fp64 butterflies for ILP.
    vfloat4 xv[9][3];
#pragma unroll
    for (int it = 0; it < 9; ++it) {
      const int row = i0 - kHalo + wv + 3 * it;  // wave-striped: lr = wv+3*it
#pragma unroll
      for (int k = 0; k < 3; ++k)
        xv[it][k] = *(const vfloat4*)(xb + (size_t)row * kD + 4 * lane + 256 * k);
    }
    double p[9];
#pragma unroll
    for (int it = 0; it < 9; ++it) {
      double q = 0.0;
#pragma unroll
      for (int k = 0; k < 3; ++k) {
        q += (double)xv[it][k].x * (double)w[k].x + (double)xv[it][k].y * (double)w[k].y +
             (double)xv[it][k].z * (double)w[k].z + (double)xv[it][k].w * (double)w[k].w;
      }
      p[it] = q;
    }
#pragma unroll
    for (int s = 32; s >= 1; s >>= 1) {
#pragma unroll
      for (int it = 0; it < 9; ++it) p[it] += __shfl_xor(p[it], s, 64);
    }
    if (lane == 0) {
#pragma unroll
      for (int it = 0; it < 9; ++it) {
        const int lr = wv + 3 * it;
        s_ud[lr] = p[it];
        s_uf[lr] = (float)p[it];
      }
    }
  } else {
    // Cold path (first chunk of each batch): guard rows < 0.
#pragma unroll
    for (int it = 0; it < 9; ++it) {
      const int lr = wv + 3 * it;
      const int row = i0 - kHalo + lr;
      double p = 0.0;
      if (row >= 0) {  // wave-uniform
        vfloat4 xv[3];
#pragma unroll
        for (int k = 0; k < 3; ++k)
          xv[k] = *(const vfloat4*)(xb + (size_t)row * kD + 4 * lane + 256 * k);
#pragma unroll
        for (int k = 0; k < 3; ++k) {
          p += (double)xv[k].x * (double)w[k].x + (double)xv[k].y * (double)w[k].y +
               (double)xv[k].z * (double)w[k].z + (double)xv[k].w * (double)w[k].w;
        }
#pragma unroll
        for (int s = 32; s >= 1; s >>= 1) p += __shfl_xor(p, s, 64);
      }
      if (lane == 0) {
        s_ud[lr] = p;
        s_uf[lr] = (float)p;
      }
    }
  }
  __syncthreads();

  // u -> registers (27 floats; indices static after unroll)
  float uf[kRows];
#pragma unroll
  for (int r = 0; r < kRows; ++r) uf[r] = s_uf[r];

  // Threads 0..15: scale_i = u_i / (u_i * wsum_i + eps), fp64 (ascending j,
  // rows<0 contribute exact 0.0 == old skip semantics).
  if (tid < kT) {
    double wsum = 0.0;
#pragma unroll
    for (int k = 0; k < kW; ++k) wsum += s_ud[tid + k];
    const double uu = s_ud[tid + kHalo];
    s_scale[tid] = (float)(uu / (uu * wsum + (double)kEps));
  }

  // Halo ring loads — independent of s_scale, L1/L2-hot from phase A.
  const int c0 = 4 * tid;
  vfloat4 ring[kW];
#pragma unroll
  for (int r = 0; r < kHalo; ++r) {  // local rows 0..10 = global i0-11..i0-1
    const int row = i0 - kHalo + r;
    vfloat4 v = {0.f, 0.f, 0.f, 0.f};
    if (row >= 0) v = *(const vfloat4*)(xb + (size_t)row * kD + c0);
    ring[r] = v;
  }
  __syncthreads();

  float sc[kT];
#pragma unroll
  for (int t = 0; t < kT; ++t) sc[t] = s_scale[t];

  // ---------------- Phase B: banded v (unchanged structure) ----------------
#pragma unroll
  for (int t = 0; t < kT; ++t) {
    const int i = i0 + t;
    const int r = kHalo + t;  // local row 11..26
    ring[r % kW] = *(const vfloat4*)(xb + (size_t)i * kD + c0);
    vfloat4 acc = {0.f, 0.f, 0.f, 0.f};
#pragma unroll
    for (int j = 0; j < kW; ++j) {
      const float uu = uf[r - j];
      const vfloat4 xv = ring[(r - j) % kW];
      acc.x += uu * xv.x; acc.y += uu * xv.y;
      acc.z += uu * xv.z; acc.w += uu * xv.w;
    }
    const float s = sc[t];
    vfloat4 o = {s * acc.x, s * acc.y, s * acc.z, s * acc.w};
    // output never re-read: don't pollute L2/L3 (keep x resident)
    __builtin_nontemporal_store(o, (vfloat4*)(ob + (size_t)i * kD + c0));
  }
}

extern "C" void kernel_launch(void* const* d_in, const int* in_sizes, int n_in,
                              void* d_out, int out_size, void* d_ws, size_t ws_size,
                              hipStream_t stream) {
  const float* x = (const float*)d_in[0];
  const float* Wa = (const float*)d_in[1];
  float* out = (float*)d_out;
  (void)d_ws; (void)ws_size;

  fused_banded_kernel<<<kGrid, kThreads, 0, stream>>>(x, Wa, out);
}

// Round 2
// 184.369 us; speedup vs baseline: 1.0778x; 1.0777x over previous
//
#include <hip/hip_runtime.h>

// Native clang vector: layout-identical to float4, accepted by nontemporal builtins.
typedef float vfloat4 __attribute__((ext_vector_type(4)));

namespace {
constexpr int kB = 8;
constexpr int kL = 4096;
constexpr int kD = 768;
constexpr int kW = 12;           // ATTN_WIDTH
constexpr int kHalo = kW - 1;    // 11
constexpr float kEps = 1e-7f;

constexpr int kT = 16;                   // output rows per block
constexpr int kRows = kT + kHalo;        // 27 rows touched per block
constexpr int kThreads = 192;            // 192*4 == kD
constexpr int kChunks = kL / kT;         // 256
constexpr int kGrid = kB * kChunks;      // 2048 blocks
constexpr int kGroups = kThreads / 4;    // 48 four-lane column groups
}

// One-pass fused kernel: x is read EXACTLY ONCE per block.
// Each thread owns columns c0..c0+3 of all 27 rows (halo + 16 outputs) in
// registers. u[row] = x[row] @ Wa is computed from those same registers:
//   fp64 per-thread dot4  ->  2-step fp64 shfl_xor (4-lane groups)
//   -> 48 group-partials to LDS -> 27 threads finish the 48-way fp64 sum.
// Phase B (banded accumulate) then runs entirely from registers.
// This removes round-1's phase-B re-read of x (which missed L2: FETCH was
// 160 MB vs 100.7 MB compulsory).
//
// Numerics: u is fp64 end-to-end (products, shuffle reduce, LDS sum, wsum,
// scale) — summation order differs from the reference kernel but fp64 error
// (~1e-15 rel) is far below the fp32 sensitivity that mandated fp64.
__global__ __launch_bounds__(kThreads, 3) void fused_onepass_kernel(
    const float* __restrict__ x, const float* __restrict__ Wa,
    float* __restrict__ out) {
  // +1 double pad: stage-2 rows are 49*8 B apart -> consecutive rows 2 banks
  // apart -> worst 2-way conflict (free, m136).
  __shared__ double s_part[kRows][kGroups + 1];  // 27 x 49 x 8 = 10.6 KB
  __shared__ double s_ud[kRows];
  __shared__ float s_scale[kT];

  const int blk = blockIdx.x;
  const int b = blk / kChunks;
  const int i0 = (blk % kChunks) * kT;
  const float* xb = x + (size_t)b * kL * kD;
  float* ob = out + (size_t)b * kL * kD;
  const int tid = threadIdx.x;
  const int c0 = 4 * tid;

  const vfloat4 w4 = *(const vfloat4*)(Wa + c0);

  // ---- The only x reads in the kernel: 27 independent dwordx4 per thread.
  vfloat4 xr[kRows];
  if (i0 >= kHalo) {
    // Hot path (2040/2048 blocks): no guards, all loads issued up front.
#pragma unroll
    for (int r = 0; r < kRows; ++r)
      xr[r] = *(const vfloat4*)(xb + (size_t)(i0 - kHalo + r) * kD + c0);
  } else {
    // First chunk of each batch: rows < 0 are zero (matches padded cumsum).
#pragma unroll
    for (int r = 0; r < kRows; ++r) {
      const int row = i0 - kHalo + r;
      vfloat4 v = {0.f, 0.f, 0.f, 0.f};
      if (row >= 0) v = *(const vfloat4*)(xb + (size_t)row * kD + c0);
      xr[r] = v;
    }
  }

  // ---- Phase A: u partials from the registers we already loaded.
#pragma unroll
  for (int r = 0; r < kRows; ++r) {
    double p = (double)xr[r].x * (double)w4.x + (double)xr[r].y * (double)w4.y +
               (double)xr[r].z * (double)w4.z + (double)xr[r].w * (double)w4.w;
    // 4-lane group reduce (lanes differing in bits 0..1 == columns 16g..16g+15)
    p += __shfl_xor(p, 1, 64);
    p += __shfl_xor(p, 2, 64);
    if ((tid & 3) == 0) s_part[r][tid >> 2] = p;
  }
  __syncthreads();

  // ---- Stage 2: one thread per row sums the 48 group-partials (fp64).
  if (tid < kRows) {
    double a0 = 0.0, a1 = 0.0, a2 = 0.0, a3 = 0.0;
#pragma unroll
    for (int g = 0; g < kGroups; g += 4) {
      a0 += s_part[tid][g + 0];
      a1 += s_part[tid][g + 1];
      a2 += s_part[tid][g + 2];
      a3 += s_part[tid][g + 3];
    }
    s_ud[tid] = (a0 + a1) + (a2 + a3);
  }
  __syncthreads();

  // Threads 0..15: scale_i = u_i / (u_i * wsum_i + eps), fp64.
  if (tid < kT) {
    double wsum = 0.0;
#pragma unroll
    for (int k = 0; k < kW; ++k) wsum += s_ud[tid + k];
    const double uu = s_ud[tid + kHalo];
    s_scale[tid] = (float)(uu / (uu * wsum + (double)kEps));
  }

  // Broadcast u -> fp32 regs (27 ds_read_b64 broadcasts; s_ud valid since
  // the last barrier).
  float uf[kRows];
#pragma unroll
  for (int r = 0; r < kRows; ++r) uf[r] = (float)s_ud[r];
  __syncthreads();  // covers the s_scale writes above

  // ---- Phase B: banded accumulate, entirely register-resident.
#pragma unroll
  for (int t = 0; t < kT; ++t) {
    vfloat4 acc = {0.f, 0.f, 0.f, 0.f};
#pragma unroll
    for (int j = 0; j < kW; ++j) {
      const int r = kHalo + t - j;  // static after unroll
      const float uu = uf[r];
      const vfloat4 xv = xr[r];
      acc.x += uu * xv.x; acc.y += uu * xv.y;
      acc.z += uu * xv.z; acc.w += uu * xv.w;
    }
    const float s = s_scale[t];  // b32 broadcast, saves 16 VGPRs vs regs
    vfloat4 o = {s * acc.x, s * acc.y, s * acc.z, s * acc.w};
    // output never re-read: don't pollute L2/L3 (keep x resident)
    __builtin_nontemporal_store(o, (vfloat4*)(ob + (size_t)(i0 + t) * kD + c0));
  }
}

extern "C" void kernel_launch(void* const* d_in, const int* in_sizes, int n_in,
                              void* d_out, int out_size, void* d_ws, size_t ws_size,
                              hipStream_t stream) {
  const float* x = (const float*)d_in[0];
  const float* Wa = (const float*)d_in[1];
  float* out = (float*)d_out;
  (void)d_ws; (void)ws_size;

  fused_onepass_kernel<<<kGrid, kThreads, 0, stream>>>(x, Wa, out);
}

// Round 3
// 184.301 us; speedup vs baseline: 1.0782x; 1.0004x over previous
//
#include <hip/hip_runtime.h>

// Native clang vector: layout-identical to float4, accepted by nontemporal builtins.
typedef float vfloat4 __attribute__((ext_vector_type(4)));

namespace {
constexpr int kB = 8;
constexpr int kL = 4096;
constexpr int kD = 768;
constexpr int kW = 12;           // ATTN_WIDTH
constexpr int kHalo = kW - 1;    // 11
constexpr float kEps = 1e-7f;

constexpr int kT = 16;                   // output rows per chunk
constexpr int kC = 2;                    // chunks per block
constexpr int kS = kT * kC;              // 32-row strip per block
constexpr int kRing = kT + kHalo;        // 27 register ring slots
constexpr int kThreads = 192;            // 192*4 == kD
constexpr int kStrips = kL / kS;         // 128
constexpr int kGrid = kB * kStrips;      // 1024 -> 4 blocks/CU
constexpr int kGroups = kThreads / 4;    // 48 four-lane column groups
constexpr int kUMask = 31;               // 32-slot LDS u-ring (power of 2)
}

__device__ __forceinline__ double dot4d(const vfloat4 a, const vfloat4 w) {
  return (double)a.x * (double)w.x + (double)a.y * (double)w.y +
         (double)a.z * (double)w.z + (double)a.w * (double)w.w;
}

// Persistent 32-row strip per block. The 27-row register ring is loaded once
// (prologue), then chunk c+1's rows are prefetched into the slots freed by
// chunk c's outputs, DURING phase B, and consumed by the next u-dot with no
// intervening barrier — loads overlap compute instead of serializing.
// u lives in a 32-slot LDS ring (mod-32 reuse is race-free: every
// write/read overlap is separated by a barrier; live window is 27 < 32).
//
// Numerics: u is fp64 end-to-end (dot4 -> 4-lane shfl reduce -> 48-partial
// LDS sum -> wsum/scale), same as the passing round-2 kernel.
__global__ __launch_bounds__(kThreads, 3) void banded_strip_kernel(
    const float* __restrict__ x, const float* __restrict__ Wa,
    float* __restrict__ out) {
  // +1 double pad: stage-2 rows 49*8 B apart -> 2-way conflict max (free).
  __shared__ double s_part[kRing][kGroups + 1];  // 10.6 KB
  __shared__ double s_ud[kUMask + 1];
  __shared__ float s_uf[kUMask + 1];
  __shared__ float s_scale[kT];

  const int blk = blockIdx.x;
  const int b = blk / kStrips;
  const int s0 = (blk % kStrips) * kS;
  const float* xb = x + (size_t)b * kL * kD;
  float* ob = out + (size_t)b * kL * kD;
  const int tid = threadIdx.x;
  const int c0 = 4 * tid;
  const vfloat4 w4 = *(const vfloat4*)(Wa + c0);

  // ---- Prologue: ring slots 0..26 = rows s0-11 .. s0+15 (only load burst).
  vfloat4 xr[kRing];
  if (s0 >= kHalo) {
#pragma unroll
    for (int r = 0; r < kRing; ++r)
      xr[r] = *(const vfloat4*)(xb + (size_t)(s0 - kHalo + r) * kD + c0);
  } else {
    // First strip of each batch: rows < 0 are zero (matches padded cumsum).
#pragma unroll
    for (int r = 0; r < kRing; ++r) {
      const int row = s0 - kHalo + r;
      vfloat4 v = {0.f, 0.f, 0.f, 0.f};
      if (row >= 0) v = *(const vfloat4*)(xb + (size_t)row * kD + c0);
      xr[r] = v;
    }
  }

  // u-partials for all 27 prologue rows: fp64 dot4 + 4-lane group reduce.
#pragma unroll
  for (int r = 0; r < kRing; ++r) {
    double p = dot4d(xr[r], w4);
    p += __shfl_xor(p, 1, 64);
    p += __shfl_xor(p, 2, 64);
    if ((tid & 3) == 0) s_part[r][tid >> 2] = p;
  }
  __syncthreads();
  // Stage 2: 4 threads per row sum 12 partials each, 2-step shfl finish.
  if (tid < 4 * kRing) {  // 108 threads; 4-lane groups never cross a wave
    const int r = tid >> 2, q = tid & 3;
    double a = 0.0;
#pragma unroll
    for (int g = 0; g < 12; ++g) a += s_part[r][q * 12 + g];
    a += __shfl_xor(a, 1, 64);
    a += __shfl_xor(a, 2, 64);
    if (q == 0) { s_ud[r] = a; s_uf[r] = (float)a; }
  }
  __syncthreads();

#pragma unroll
  for (int c = 0; c < kC; ++c) {
    // scale_i = u_i / (u_i * wsum_i + eps), fp64, rows of chunk c.
    if (tid < kT) {
      double wsum = 0.0;
#pragma unroll
      for (int k = 0; k < kW; ++k) wsum += s_ud[(16 * c + tid + k) & kUMask];
      const double uu = s_ud[(16 * c + tid + kHalo) & kUMask];
      s_scale[tid] = (float)(uu / (uu * wsum + (double)kEps));
    }
    __syncthreads();

    // ---- Phase B for chunk c, prefetching chunk c+1 into freed slots.
#pragma unroll
    for (int t = 0; t < kT; ++t) {
      vfloat4 acc = {0.f, 0.f, 0.f, 0.f};
#pragma unroll
      for (int j = 0; j < kW; ++j) {
        const int l = 16 * c + t + kHalo - j;  // block-local row index
        const float uu = s_uf[l & kUMask];     // broadcast read
        const vfloat4 xv = xr[l % kRing];      // static after unroll
        acc.x += uu * xv.x; acc.y += uu * xv.y;
        acc.z += uu * xv.z; acc.w += uu * xv.w;
      }
      const float s = s_scale[t];
      vfloat4 o = {s * acc.x, s * acc.y, s * acc.z, s * acc.w};
      // output never re-read: don't pollute L2/L3 (keep x resident)
      __builtin_nontemporal_store(o, (vfloat4*)(ob + (size_t)(s0 + 16 * c + t) * kD + c0));
      if (c + 1 < kC) {
        // slot (16c+t)%27 was last read by THIS output; refill with the
        // next-chunk row. Consumed after the loop, before any barrier.
        const int lnew = kRing + 16 * c + t;   // row s0 + 16 + 16c + t
        xr[lnew % kRing] =
            *(const vfloat4*)(xb + (size_t)(s0 - kHalo + lnew) * kD + c0);
      }
    }

    if (c + 1 < kC) {
      // u-partials for the 16 prefetched rows (loads still in flight from
      // phase B — consumed here with no barrier in between).
#pragma unroll
      for (int t = 0; t < kT; ++t) {
        const int lnew = kRing + 16 * c + t;
        double p = dot4d(xr[lnew % kRing], w4);
        p += __shfl_xor(p, 1, 64);
        p += __shfl_xor(p, 2, 64);
        if ((tid & 3) == 0) s_part[t][tid >> 2] = p;
      }
      __syncthreads();
      if (tid < 64) {
        const int r = tid >> 2, q = tid & 3;
        double a = 0.0;
#pragma unroll
        for (int g = 0; g < 12; ++g) a += s_part[r][q * 12 + g];
        a += __shfl_xor(a, 1, 64);
        a += __shfl_xor(a, 2, 64);
        if (q == 0) {
          const int l = kRing + 16 * c + r;
          s_ud[l & kUMask] = a;
          s_uf[l & kUMask] = (float)a;
        }
      }
      __syncthreads();
    }
  }
}

extern "C" void kernel_launch(void* const* d_in, const int* in_sizes, int n_in,
                              void* d_out, int out_size, void* d_ws, size_t ws_size,
                              hipStream_t stream) {
  const float* x = (const float*)d_in[0];
  const float* Wa = (const float*)d_in[1];
  float* out = (float*)d_out;
  (void)d_ws; (void)ws_size;

  banded_strip_kernel<<<kGrid, kThreads, 0, stream>>>(x, Wa, out);
}